// Round 10
// baseline (471.504 us; speedup 1.0000x reference)
//
#include <hip/hip_runtime.h>
#include <hip/hip_fp16.h>

#define NODES 100000
#define NBKT 782            // ceil(100000/128) buckets of 128 cols
#define HCHUNK 8192         // edges per bucket_hist block
#define FCHUNK 4096         // edges per bucket_fill block (256 thr x 16)

typedef unsigned short u16;
typedef unsigned int u32;

__device__ __forceinline__ float bflo(u32 v) { return __uint_as_float(v << 16); }
__device__ __forceinline__ float bfhi(u32 v) { return __uint_as_float(v & 0xFFFF0000u); }
__device__ __forceinline__ u16 f2bf(float f) {  // RNE
  u32 x = __float_as_uint(f);
  return (u16)((x + 0x7FFFu + ((x >> 16) & 1u)) >> 16);
}

// ---------------- small utils ----------------

__global__ __launch_bounds__(256) void zero_k(int* __restrict__ p, int n) {
  int i = blockIdx.x * 256 + threadIdx.x;
  if (i < n) p[i] = 0;
}

// ---------------- bucket build ----------------

__global__ __launch_bounds__(256) void bucket_hist_k(const int* __restrict__ col,
                                                     int* __restrict__ bcnt, int E) {
  __shared__ int h[NBKT];
  int t = threadIdx.x;
  for (int i = t; i < NBKT; i += 256) h[i] = 0;
  __syncthreads();
  int base = blockIdx.x * HCHUNK;
#pragma unroll 4
  for (int j = 0; j < HCHUNK / 256; ++j) {
    int i = base + j * 256 + t;
    if (i < E) atomicAdd(&h[col[i] >> 7], 1);
  }
  __syncthreads();
  for (int i = t; i < NBKT; i += 256) {
    int c = h[i];
    if (c) atomicAdd(&bcnt[i], c);
  }
}

__global__ __launch_bounds__(256) void bscan_k(const int* __restrict__ bcnt,
                                               int* __restrict__ boffs,
                                               int* __restrict__ bcurs, int nb, int E) {
  __shared__ int lds[256];
  int t = threadIdx.x;
  int base = t * 4;
  int v[4];
#pragma unroll
  for (int j = 0; j < 4; ++j) v[j] = (base + j < nb) ? bcnt[base + j] : 0;
  int s = v[0] + v[1] + v[2] + v[3];
  lds[t] = s;
  __syncthreads();
  for (int off = 1; off < 256; off <<= 1) {
    int y = (t >= off) ? lds[t - off] : 0;
    __syncthreads();
    lds[t] += y;
    __syncthreads();
  }
  int excl = lds[t] - s;
#pragma unroll
  for (int j = 0; j < 4; ++j) {
    int i = base + j;
    if (i < nb) { boffs[i] = excl; bcurs[i] = excl; }
    excl += v[j];
  }
  if (t == 255) boffs[nb] = E;
}

// scatter packed records (colLow<<17 | row) into bucket regions.
__global__ __launch_bounds__(256) void bucket_fill_k(const int* __restrict__ row,
                                                     const int* __restrict__ col,
                                                     int* __restrict__ bcurs,
                                                     u32* __restrict__ recs, int E) {
  __shared__ int lcnt[NBKT];
  __shared__ int lbase[NBKT];
  int t = threadIdx.x;
  int base = blockIdx.x * FCHUNK;
  for (int i = t; i < NBKT; i += 256) lcnt[i] = 0;
  __syncthreads();
  u32 rec[FCHUNK / 256];
  u32 meta[FCHUNK / 256];
#pragma unroll
  for (int j = 0; j < FCHUNK / 256; ++j) {
    int i = base + j * 256 + t;
    if (i < E) {
      int r = row[i], c = col[i];
      int b = c >> 7;
      rec[j] = (u32)r | ((u32)(c & 127) << 17);
      int lr = atomicAdd(&lcnt[b], 1);
      meta[j] = (u32)lr | ((u32)b << 16);
    } else {
      meta[j] = 0xFFFFFFFFu;
    }
  }
  __syncthreads();
  for (int i = t; i < NBKT; i += 256) {
    int c = lcnt[i];
    lbase[i] = c ? atomicAdd(&bcurs[i], c) : 0;
  }
  __syncthreads();
#pragma unroll
  for (int j = 0; j < FCHUNK / 256; ++j) {
    if (meta[j] != 0xFFFFFFFFu) {
      int b = meta[j] >> 16;
      int lr = meta[j] & 0xFFFF;
      recs[lbase[b] + lr] = rec[j];
    }
  }
}

// records (bucketed by col) -> per-node CSR (offs, adj) + dis. One block per bucket.
__global__ __launch_bounds__(256) void csr_k(const u32* __restrict__ recs,
                                             const int* __restrict__ boffs,
                                             int* __restrict__ offs, int* __restrict__ adj,
                                             float* __restrict__ dis, int N, int E) {
  __shared__ int cnt[128];
  __shared__ int sa[128], sb[128];
  __shared__ int cur[128];
  int b = blockIdx.x, t = threadIdx.x;
  if (t < 128) cnt[t] = 0;
  __syncthreads();
  int s = boffs[b], e = boffs[b + 1];
  for (int i = s + t; i < e; i += 256) atomicAdd(&cnt[recs[i] >> 17], 1);
  __syncthreads();
  if (t < 128) sa[t] = cnt[t];
  __syncthreads();
#pragma unroll
  for (int off = 1; off < 128; off <<= 1) {
    if (t < 128) sb[t] = sa[t] + ((t >= off) ? sa[t - off] : 0);
    __syncthreads();
    if (t < 128) sa[t] = sb[t];
    __syncthreads();
  }
  if (t < 128) {
    int c = b * 128 + t;
    if (c < N) {
      int excl = sa[t] - cnt[t];
      offs[c] = s + excl;
      cur[t] = s + excl;
      dis[c] = rsqrtf((float)(cnt[t] + 1));  // +1 self loop
    }
  }
  if (b == 0 && t == 0) offs[N] = E;
  __syncthreads();
  for (int i = s + t; i < e; i += 256) {
    u32 r = recs[i];
    int p = atomicAdd(&cur[r >> 17], 1);
    adj[p] = (int)(r & 0x1FFFF);
  }
}

// ---------------- GEMM (NOUT=64): G[node,:] = (X[node,:] @ W) * dis[node] ----------------
template <int K, int NK, int OUTFMT>
__global__ __launch_bounds__(256, 2) void gemm64_k(const float* __restrict__ X,
                                                   const float* __restrict__ W,
                                                   const float* __restrict__ dis,
                                                   u16* __restrict__ G, int n) {
  static_assert(K == NK * 4, "NT=4");
  __shared__ float ws[K * 64];
  int t = threadIdx.x;
  for (int i = t; i < K * 64; i += 256) ws[i] = W[i];
  __syncthreads();
  int q = t & 3, g = t >> 2;
  int b0 = blockIdx.x * 128;
  int n0 = b0 + g, n1 = b0 + 64 + g;
  int c0 = (n0 < n) ? n0 : 0, c1 = (n1 < n) ? n1 : 0;
  float xv0[NK], xv1[NK];
  const float* p0 = X + (size_t)c0 * K + q * NK;
  const float* p1 = X + (size_t)c1 * K + q * NK;
  if constexpr (NK % 4 == 0) {
#pragma unroll
    for (int i = 0; i < NK / 4; ++i) {
      *(float4*)&xv0[4 * i] = *(const float4*)(p0 + 4 * i);
      *(float4*)&xv1[4 * i] = *(const float4*)(p1 + 4 * i);
    }
  } else {
#pragma unroll
    for (int i = 0; i < NK; ++i) { xv0[i] = p0[i]; xv1[i] = p1[i]; }
  }
  float acc0[16], acc1[16];
#pragma unroll
  for (int j = 0; j < 16; ++j) { acc0[j] = 0.f; acc1[j] = 0.f; }
  for (int qq = 0; qq < 4; ++qq) {
    const float* wbase = ws + (size_t)qq * NK * 64 + q * 16;
#pragma unroll
    for (int i = 0; i < NK; ++i) {
      float a0 = __shfl(xv0[i], qq, 4);
      float a1 = __shfl(xv1[i], qq, 4);
      const float* wr = wbase + i * 64;
#pragma unroll
      for (int j = 0; j < 16; ++j) {
        float w = wr[j];
        acc0[j] = fmaf(a0, w, acc0[j]);
        acc1[j] = fmaf(a1, w, acc1[j]);
      }
    }
  }
  uint4* G4 = (uint4*)G;
  {
    if (n0 < n) {
      float sc = dis[n0];
      u32 os[8];
#pragma unroll
      for (int j = 0; j < 8; ++j) {
        float v0 = acc0[2 * j] * sc, v1 = acc0[2 * j + 1] * sc;
        u16 lo = (OUTFMT == 1) ? f2bf(v0) : __half_as_ushort(__float2half(v0));
        u16 hi = (OUTFMT == 1) ? f2bf(v1) : __half_as_ushort(__float2half(v1));
        os[j] = (u32)lo | ((u32)hi << 16);
      }
      size_t rb = (size_t)n0 * 8 + q * 2;
      G4[rb]     = make_uint4(os[0], os[1], os[2], os[3]);
      G4[rb + 1] = make_uint4(os[4], os[5], os[6], os[7]);
    }
    if (n1 < n) {
      float sc = dis[n1];
      u32 os[8];
#pragma unroll
      for (int j = 0; j < 8; ++j) {
        float v0 = acc1[2 * j] * sc, v1 = acc1[2 * j + 1] * sc;
        u16 lo = (OUTFMT == 1) ? f2bf(v0) : __half_as_ushort(__float2half(v0));
        u16 hi = (OUTFMT == 1) ? f2bf(v1) : __half_as_ushort(__float2half(v1));
        os[j] = (u32)lo | ((u32)hi << 16);
      }
      size_t rb = (size_t)n1 * 8 + q * 2;
      G4[rb]     = make_uint4(os[0], os[1], os[2], os[3]);
      G4[rb + 1] = make_uint4(os[4], os[5], os[6], os[7]);
    }
  }
}

// ---------------- GEMM (final, NOUT=18, fp16 out): 2 threads/node, outs split 10/8 ----------------
__global__ __launch_bounds__(256, 2) void gemm18_k(const float* __restrict__ X,  // K=64
                                                   const float* __restrict__ W,
                                                   const float* __restrict__ dis,
                                                   u16* __restrict__ G, int n) {
  __shared__ float ws[64 * 18];
  int t = threadIdx.x;
  for (int i = t; i < 64 * 18; i += 256) ws[i] = W[i];
  __syncthreads();
  int q = t & 1, g = t >> 1;
  int b0 = blockIdx.x * 128;
  int node = b0 + g;
  int cn = (node < n) ? node : 0;
  float xv[32];
  const float* p = X + (size_t)cn * 64 + q * 32;
#pragma unroll
  for (int i = 0; i < 8; ++i) *(float4*)&xv[4 * i] = *(const float4*)(p + 4 * i);
  int cnt = q ? 8 : 10;
  float acc[10];
#pragma unroll
  for (int j = 0; j < 10; ++j) acc[j] = 0.f;
  for (int qq = 0; qq < 2; ++qq) {
    const float* wbase = ws + (size_t)qq * 32 * 18 + q * 10;
#pragma unroll
    for (int i = 0; i < 32; ++i) {
      float a = __shfl(xv[i], qq, 2);
      const float* wr = wbase + i * 18;
#pragma unroll
      for (int j = 0; j < 10; ++j)
        if (j < cnt) acc[j] = fmaf(a, wr[j], acc[j]);
    }
  }
  if (node >= n) return;
  float sc = dis[node];
  u32* G32 = (u32*)G;
  if (q == 0) {
    u32 os[5];
#pragma unroll
    for (int j = 0; j < 5; ++j) {
      u16 lo = __half_as_ushort(__float2half(acc[2 * j] * sc));
      u16 hi = __half_as_ushort(__float2half(acc[2 * j + 1] * sc));
      os[j] = (u32)lo | ((u32)hi << 16);
    }
#pragma unroll
    for (int j = 0; j < 5; ++j) G32[(size_t)node * 9 + j] = os[j];
  } else {
    u32 os[4];
#pragma unroll
    for (int j = 0; j < 4; ++j) {
      u16 lo = __half_as_ushort(__float2half(acc[2 * j] * sc));
      u16 hi = __half_as_ushort(__float2half(acc[2 * j + 1] * sc));
      os[j] = (u32)lo | ((u32)hi << 16);
    }
#pragma unroll
    for (int j = 0; j < 4; ++j) G32[(size_t)node * 9 + 5 + j] = os[j];
  }
}

// ---------------- aggregation (hidden): 4 edges per wave-gather, 32 edges in flight ----------------
// wave = 4 quarters of 16 lanes; quarter qt owns edge i+4k+qt; lane loads uint2 = 4 bf16 feats.
// acc[4] per lane (feats 4*sub..4*sub+3); combine quarters via shfl_xor(16),(32).
__global__ __launch_bounds__(256) void agg_bf16_k(const u16* __restrict__ g,
                                                  const int* __restrict__ offs,
                                                  const int* __restrict__ adj,
                                                  const float* __restrict__ dis,
                                                  const float* __restrict__ bias,
                                                  float* __restrict__ out, int n) {
  int node = blockIdx.x * 4 + (threadIdx.x >> 6);
  int lane = threadIdx.x & 63;
  int qt = lane >> 4, sub = lane & 15;
  if (node >= n) return;
  const uint2* G2 = (const uint2*)g;  // row = 16 x uint2 (128B)
  float a0 = 0.f, a1 = 0.f, a2 = 0.f, a3 = 0.f;
  int s = offs[node], e = offs[node + 1];
  int i = s;
  for (; i + 32 <= e; i += 32) {  // 8 quad-gathers in flight
    int r0 = adj[i + qt];
    int r1 = adj[i + 4 + qt];
    int r2 = adj[i + 8 + qt];
    int r3 = adj[i + 12 + qt];
    int r4 = adj[i + 16 + qt];
    int r5 = adj[i + 20 + qt];
    int r6 = adj[i + 24 + qt];
    int r7 = adj[i + 28 + qt];
    uint2 v0 = G2[(r0 << 4) + sub];
    uint2 v1 = G2[(r1 << 4) + sub];
    uint2 v2 = G2[(r2 << 4) + sub];
    uint2 v3 = G2[(r3 << 4) + sub];
    uint2 v4 = G2[(r4 << 4) + sub];
    uint2 v5 = G2[(r5 << 4) + sub];
    uint2 v6 = G2[(r6 << 4) + sub];
    uint2 v7 = G2[(r7 << 4) + sub];
    a0 += ((bflo(v0.x) + bflo(v1.x)) + (bflo(v2.x) + bflo(v3.x))) +
          ((bflo(v4.x) + bflo(v5.x)) + (bflo(v6.x) + bflo(v7.x)));
    a1 += ((bfhi(v0.x) + bfhi(v1.x)) + (bfhi(v2.x) + bfhi(v3.x))) +
          ((bfhi(v4.x) + bfhi(v5.x)) + (bfhi(v6.x) + bfhi(v7.x)));
    a2 += ((bflo(v0.y) + bflo(v1.y)) + (bflo(v2.y) + bflo(v3.y))) +
          ((bflo(v4.y) + bflo(v5.y)) + (bflo(v6.y) + bflo(v7.y)));
    a3 += ((bfhi(v0.y) + bfhi(v1.y)) + (bfhi(v2.y) + bfhi(v3.y))) +
          ((bfhi(v4.y) + bfhi(v5.y)) + (bfhi(v6.y) + bfhi(v7.y)));
  }
  for (; i + 4 <= e; i += 4) {
    int r = adj[i + qt];
    uint2 v = G2[(r << 4) + sub];
    a0 += bflo(v.x); a1 += bfhi(v.x); a2 += bflo(v.y); a3 += bfhi(v.y);
  }
  if (i < e) {  // tail: m = e-i in 1..3; quarter qt contributes iff qt < m
    int m = e - i;
    int idx = (qt < m) ? (i + qt) : i;
    int r = adj[idx];
    uint2 v = G2[(r << 4) + sub];
    if (qt < m) { a0 += bflo(v.x); a1 += bfhi(v.x); a2 += bflo(v.y); a3 += bfhi(v.y); }
  }
  // combine quarters
  a0 += __shfl_xor(a0, 16, 64); a0 += __shfl_xor(a0, 32, 64);
  a1 += __shfl_xor(a1, 16, 64); a1 += __shfl_xor(a1, 32, 64);
  a2 += __shfl_xor(a2, 16, 64); a2 += __shfl_xor(a2, 32, 64);
  a3 += __shfl_xor(a3, 16, 64); a3 += __shfl_xor(a3, 32, 64);
  // self loop (g pre-scaled by dis[node]) — post-reduce, consistent across lanes
  uint2 vs = G2[(node << 4) + sub];
  a0 += bflo(vs.x); a1 += bfhi(vs.x); a2 += bflo(vs.y); a3 += bfhi(vs.y);
  float d = dis[node];
  float4 b4 = *(const float4*)(bias + 4 * sub);
  if (qt == 0) {
    float4 o;
    o.x = fmaxf(fmaf(d, a0, b4.x), 0.f);
    o.y = fmaxf(fmaf(d, a1, b4.y), 0.f);
    o.z = fmaxf(fmaf(d, a2, b4.z), 0.f);
    o.w = fmaxf(fmaf(d, a3, b4.w), 0.f);
    *(float4*)(out + node * 64 + 4 * sub) = o;  // 16 lanes x 16B = 256B
  }
}

// ---------------- aggregation (final, 18-wide fp16 table): 3 edges per wave-gather ----------------
__global__ __launch_bounds__(256) void agg_f16o_k(const u16* __restrict__ g,
                                                  const int* __restrict__ offs,
                                                  const int* __restrict__ adj,
                                                  const float* __restrict__ dis,
                                                  const float* __restrict__ bias,
                                                  float* __restrict__ out, int n) {
  int node = blockIdx.x * 4 + (threadIdx.x >> 6);
  int lane = threadIdx.x & 63;
  int e3 = lane / 18;              // 0..2 active, 3 = idle (lanes 54..63)
  int f = lane - e3 * 18;
  if (node >= n) return;
  const __half* gh = (const __half*)g;
  bool act = e3 < 3;
  float acc = 0.f;
  int s = offs[node], e = offs[node + 1];
  int i = s;
  if (act) {
    for (; i + 12 <= e; i += 12) {  // 4 triple-gathers in flight
      int r0 = adj[i + e3];
      int r1 = adj[i + 3 + e3];
      int r2 = adj[i + 6 + e3];
      int r3 = adj[i + 9 + e3];
      float x0 = __half2float(gh[r0 * 18 + f]);
      float x1 = __half2float(gh[r1 * 18 + f]);
      float x2 = __half2float(gh[r2 * 18 + f]);
      float x3 = __half2float(gh[r3 * 18 + f]);
      acc += (x0 + x1) + (x2 + x3);
    }
    for (; i + 3 <= e; i += 3) {
      int r = adj[i + e3];
      acc += __half2float(gh[r * 18 + f]);
    }
    if (i < e) {  // tail m in 1..2
      int m = e - i;
      int idx = (e3 < m) ? (i + e3) : i;
      int r = adj[idx];
      float x = __half2float(gh[r * 18 + f]);
      if (e3 < m) acc += x;
    }
  }
  // reduce across the 3 edge-groups (lanes l, l+18, l+36) — all lanes execute
  float t1 = __shfl(acc, lane + 18, 64);
  float t2 = __shfl(acc, lane + 36, 64);
  if (lane < 18) {
    float total = acc + t1 + t2;
    total += __half2float(gh[node * 18 + lane]);  // self loop
    float v = fmaf(dis[node], total, bias[lane]);
    out[node * 18 + lane] = v;
  }
}

// ---------------- launch ----------------

extern "C" void kernel_launch(void* const* d_in, const int* in_sizes, int n_in,
                              void* d_out, int out_size, void* d_ws, size_t ws_size,
                              hipStream_t stream) {
  const float* x  = (const float*)d_in[0];
  const int*   ei = (const int*)d_in[1];
  const float* W1 = (const float*)d_in[2];
  const float* b1 = (const float*)d_in[3];
  const float* W2 = (const float*)d_in[4];
  const float* b2 = (const float*)d_in[5];
  const float* W3 = (const float*)d_in[6];
  const float* b3 = (const float*)d_in[7];
  const float* Wo = (const float*)d_in[8];
  const float* bo = (const float*)d_in[9];
  float* out = (float*)d_out;

  const int N = NODES;
  const int E = in_sizes[1] / 2;
  const int* rowp = ei;
  const int* colp = ei + E;

  char* p = (char*)d_ws;
  auto alloc = [&](size_t bytes) {
    void* r = (void*)p;
    p += (bytes + 255) & ~(size_t)255;
    return r;
  };
  int*   bcnt  = (int*)alloc((size_t)NBKT * 4);
  int*   bcurs = (int*)alloc((size_t)NBKT * 4);
  int*   boffs = (int*)alloc((size_t)(NBKT + 1) * 4);
  float* dis   = (float*)alloc((size_t)N * 4);
  int*   offs  = (int*)alloc((size_t)(N + 1) * 4);
  int*   adj   = (int*)alloc((size_t)E * 4);
  // recs (E*4 = 12.8MB) dead after csr_k; alias with bf16 gather table (N*64*2 = 12.8MB)
  u32*   recs  = (u32*)alloc((size_t)N * 64 * 2);
  u16*   gb    = (u16*)recs;
  float* h     = (float*)alloc((size_t)N * 64 * 4);   // fp32 hidden activations
  u16*   g4    = (u16*)alloc((size_t)N * 18 * 2);    // fp16 gather table, final layer

  zero_k<<<(NBKT + 255) / 256, 256, 0, stream>>>(bcnt, NBKT);
  bucket_hist_k<<<(E + HCHUNK - 1) / HCHUNK, 256, 0, stream>>>(colp, bcnt, E);
  bscan_k<<<1, 256, 0, stream>>>(bcnt, boffs, bcurs, NBKT, E);
  bucket_fill_k<<<(E + FCHUNK - 1) / FCHUNK, 256, 0, stream>>>(rowp, colp, bcurs, recs, E);
  csr_k<<<NBKT, 256, 0, stream>>>(recs, boffs, offs, adj, dis, N, E);

  int gG = (N + 127) / 128;   // 128 nodes per gemm block
  int gA = (N + 3) / 4;

  gemm64_k<100, 25, 1><<<gG, 256, 0, stream>>>(x, W1, dis, gb, N);
  agg_bf16_k<<<gA, 256, 0, stream>>>(gb, offs, adj, dis, b1, h, N);

  gemm64_k<64, 16, 1><<<gG, 256, 0, stream>>>(h, W2, dis, gb, N);
  agg_bf16_k<<<gA, 256, 0, stream>>>(gb, offs, adj, dis, b2, h, N);

  gemm64_k<64, 16, 1><<<gG, 256, 0, stream>>>(h, W3, dis, gb, N);
  agg_bf16_k<<<gA, 256, 0, stream>>>(gb, offs, adj, dis, b3, h, N);

  gemm18_k<<<gG, 256, 0, stream>>>(h, Wo, dis, g4, N);
  agg_f16o_k<<<gA, 256, 0, stream>>>(g4, offs, adj, dis, bo, out, N);
}